// Round 1
// baseline (37155.042 us; speedup 1.0000x reference)
//
#include <hip/hip_runtime.h>
#include <hip/hip_bf16.h>
#include <stdint.h>

typedef unsigned short u16;
typedef __bf16 bf16x8 __attribute__((ext_vector_type(8)));
typedef float f32x4 __attribute__((ext_vector_type(4)));

#define NT 365
#define NNODE 4096

__device__ __forceinline__ u16 f2b(float f) {
  __bf16 b = (__bf16)f;
  return __builtin_bit_cast(u16, b);
}
__device__ __forceinline__ float sigmoid_(float x) { return 1.f / (1.f + __expf(-x)); }
__device__ __forceinline__ float tanh_(float x) {
  float ax = fabsf(x);
  float e = __expf(-2.f * ax);
  float r = (1.f - e) / (1.f + e);
  return copysignf(r, x);
}

__device__ __forceinline__ void gload_lds16(const void* g, void* l) {
  __builtin_amdgcn_global_load_lds((const __attribute__((address_space(1))) void*)g,
                                   (__attribute__((address_space(3))) void*)l, 16, 0, 0);
}

// Stage RT rows x 64 bf16 cols into LDS. LDS dest is linear (global_load_lds
// requirement); the k-chunk is XOR-swizzled on the GLOBAL source so that the
// swizzled ds_read_b128 (frag_ld) is bank-conflict-free. gstride in elements.
template <int RT, int NTH>
__device__ __forceinline__ void stage_tile(const u16* __restrict__ g, int gstride,
                                           u16* lds, int tid) {
  constexpr int ITERS = (RT * 128) / (NTH * 16);
#pragma unroll
  for (int i = 0; i < ITERS; ++i) {
    int slot = i * NTH + tid;
    int off = slot << 4;               // LDS byte offset (linear)
    int row = off >> 7;                // 128 B per row (64 bf16)
    int k8 = ((off >> 4) & 7) ^ (row & 7);
    gload_lds16((const char*)(g + (size_t)row * gstride) + (k8 << 4), (char*)lds + off);
  }
}

// read 8 contiguous bf16 (one 16B chunk) for MFMA A/B fragment, undoing swizzle
__device__ __forceinline__ bf16x8 frag_ld(const u16* lds, int row, int q) {
  int off = (row << 7) + ((q ^ (row & 7)) << 4);
  return *(const bf16x8*)((const char*)lds + off);
}

__device__ __forceinline__ f32x4 mfma16(bf16x8 a, bf16x8 b, f32x4 c) {
  return __builtin_amdgcn_mfma_f32_16x16x32_bf16(a, b, c, 0, 0, 0);
}

// ---------------- init kernels ----------------

__global__ void k_convA(const float* __restrict__ A, u16* __restrict__ Abf) {
  size_t i = ((size_t)blockIdx.x * 256 + threadIdx.x) * 8;
  float4 v0 = *(const float4*)(A + i);
  float4 v1 = *(const float4*)(A + i + 4);
  union { u16 u[8]; uint4 q; } o;
  o.u[0] = f2b(v0.x); o.u[1] = f2b(v0.y); o.u[2] = f2b(v0.z); o.u[3] = f2b(v0.w);
  o.u[4] = f2b(v1.x); o.u[5] = f2b(v1.y); o.u[6] = f2b(v1.z); o.u[7] = f2b(v1.w);
  *(uint4*)(Abf + i) = o.q;
}

__global__ void k_zero(float4* __restrict__ p) {
  p[(size_t)blockIdx.x * 256 + threadIdx.x] = make_float4(0.f, 0.f, 0.f, 0.f);
}

// transpose+convert all weights to bf16 (B^T layouts for MFMA)
__global__ void k_prep(const float* __restrict__ rk, const float* __restrict__ wgh,
                       const float* __restrict__ wgc, const float* __restrict__ whc,
                       const float* __restrict__ whp, const float* __restrict__ wcc,
                       const float* __restrict__ wcp, u16* __restrict__ rkT,
                       u16* __restrict__ WgTh, u16* __restrict__ WgTc,
                       u16* __restrict__ WhT, u16* __restrict__ WcT) {
  int i = blockIdx.x * 256 + threadIdx.x;
  if (i < 262144) { int j = i >> 8, k = i & 255; rkT[i] = f2b(rk[k * 1024 + j]); return; }
  i -= 262144;
  if (i < 65536) { int j = i >> 8, k = i & 255; WgTh[i] = f2b(wgh[k * 256 + j]); return; }
  i -= 65536;
  if (i < 65536) { int j = i >> 8, k = i & 255; WgTc[i] = f2b(wgc[k * 256 + j]); return; }
  i -= 65536;
  if (i < 131072) {
    int j = i >> 9, k = i & 511;
    WhT[i] = f2b(k < 256 ? whc[k * 256 + j] : whp[(k - 256) * 256 + j]);
    return;
  }
  i -= 131072;
  if (i < 131072) {
    int j = i >> 9, k = i & 511;
    WcT[i] = f2b(k < 256 ? wcc[k * 256 + j] : wcp[(k - 256) * 256 + j]);
  }
}

// ---------------- per-step kernels ----------------

// S[4096][512] = A[4096][4096] @ HC ; B^T = HCT[512][4096]. grid(32,8) x 512thr
__global__ __launch_bounds__(512) void k_big(const u16* __restrict__ Abf,
                                             const u16* __restrict__ HCT,
                                             u16* __restrict__ Sbf) {
  __shared__ __align__(16) u16 As[128 * 64];
  __shared__ __align__(16) u16 Bs[64 * 64];
  int tid = threadIdx.x, lane = tid & 63, w = tid >> 6;
  int wr = w >> 1, wc = w & 1;  // 4x2 wave grid, wave tile 32x32
  int m0 = blockIdx.x * 128, n0 = blockIdx.y * 64;
  f32x4 acc[2][2] = {};
  int ar = wr * 32 + (lane & 15);
  int bc = wc * 32 + (lane & 15);
  for (int kt = 0; kt < 4096; kt += 64) {
    stage_tile<128, 512>(Abf + (size_t)m0 * 4096 + kt, 4096, As, tid);
    stage_tile<64, 512>(HCT + (size_t)n0 * 4096 + kt, 4096, Bs, tid);
    __syncthreads();
#pragma unroll
    for (int kk = 0; kk < 2; ++kk) {
      int q = kk * 4 + (lane >> 4);
      bf16x8 a0 = frag_ld(As, ar, q);
      bf16x8 a1 = frag_ld(As, ar + 16, q);
      bf16x8 b0 = frag_ld(Bs, bc, q);
      bf16x8 b1 = frag_ld(Bs, bc + 16, q);
      acc[0][0] = mfma16(a0, b0, acc[0][0]);
      acc[0][1] = mfma16(a0, b1, acc[0][1]);
      acc[1][0] = mfma16(a1, b0, acc[1][0]);
      acc[1][1] = mfma16(a1, b1, acc[1][1]);
    }
    __syncthreads();
  }
#pragma unroll
  for (int m = 0; m < 2; ++m)
#pragma unroll
    for (int n = 0; n < 2; ++n)
#pragma unroll
      for (int r = 0; r < 4; ++r) {
        int row = m0 + wr * 32 + m * 16 + ((lane >> 4) << 2) + r;
        int col = n0 + wc * 32 + n * 16 + (lane & 15);
        Sbf[(size_t)row * 512 + col] = f2b(acc[m][n][r]);
      }
}

// LSTM gates: z = x_t@kernel + h_prev@rkernel + b ; writes h_cur,c_cur (bf16).
// grid(64,4) x 256thr. 4 gate segments kept in the same lane.
__global__ __launch_bounds__(256) void k_gates(
    const u16* __restrict__ HCrm, const u16* __restrict__ rkT,
    const float* __restrict__ cf32, const float* __restrict__ x,
    const float* __restrict__ kern, const float* __restrict__ lbias,
    u16* __restrict__ HG, u16* __restrict__ CG, int t) {
  __shared__ __align__(16) u16 As[64 * 64];
  __shared__ __align__(16) u16 Bs[4 * 64 * 64];
  int tid = threadIdx.x, lane = tid & 63, w = tid >> 6, wr = w >> 1, wc = w & 1;
  int m0 = blockIdx.x * 64, c0 = blockIdx.y * 64;
  f32x4 acc[4][2][2] = {};
  int ar = wr * 32 + (lane & 15);
  int bc = wc * 32 + (lane & 15);
  for (int kt = 0; kt < 256; kt += 64) {
    stage_tile<64, 256>(HCrm + (size_t)m0 * 512 + kt, 512, As, tid);
#pragma unroll
    for (int i = 0; i < 8; ++i) {  // 4 segments x 64 rows of rkT
      int slot = i * 256 + tid;
      int off = slot << 4;
      int row = off >> 7;
      int k8 = ((off >> 4) & 7) ^ (row & 7);
      int grow = ((row >> 6) << 8) + c0 + (row & 63);
      gload_lds16((const char*)(rkT + (size_t)grow * 256 + kt) + (k8 << 4),
                  (char*)Bs + off);
    }
    __syncthreads();
#pragma unroll
    for (int kk = 0; kk < 2; ++kk) {
      int q = kk * 4 + (lane >> 4);
      bf16x8 a0 = frag_ld(As, ar, q);
      bf16x8 a1 = frag_ld(As, ar + 16, q);
#pragma unroll
      for (int s = 0; s < 4; ++s) {
        const u16* B = Bs + s * 4096;
        bf16x8 b0 = frag_ld(B, bc, q);
        bf16x8 b1 = frag_ld(B, bc + 16, q);
        acc[s][0][0] = mfma16(a0, b0, acc[s][0][0]);
        acc[s][0][1] = mfma16(a0, b1, acc[s][0][1]);
        acc[s][1][0] = mfma16(a1, b0, acc[s][1][0]);
        acc[s][1][1] = mfma16(a1, b1, acc[s][1][1]);
      }
    }
    __syncthreads();
  }
#pragma unroll
  for (int m = 0; m < 2; ++m) {
#pragma unroll
    for (int r = 0; r < 4; ++r) {
      int row_local = wr * 32 + m * 16 + ((lane >> 4) << 2) + r;
      int node = m0 + row_local;
      const float* xr = x + (size_t)node * (NT * 16) + t * 16;
      float xv[16];
#pragma unroll
      for (int d = 0; d < 16; ++d) xv[d] = xr[d];
#pragma unroll
      for (int n = 0; n < 2; ++n) {
        int hcol = c0 + wc * 32 + n * 16 + (lane & 15);
        float z0 = acc[0][m][n][r] + lbias[hcol];
        float z1 = acc[1][m][n][r] + lbias[256 + hcol];
        float z2 = acc[2][m][n][r] + lbias[512 + hcol];
        float z3 = acc[3][m][n][r] + lbias[768 + hcol];
#pragma unroll
        for (int d = 0; d < 16; ++d) {
          float xd = xv[d];
          z0 = fmaf(xd, kern[d * 1024 + hcol], z0);
          z1 = fmaf(xd, kern[d * 1024 + 256 + hcol], z1);
          z2 = fmaf(xd, kern[d * 1024 + 512 + hcol], z2);
          z3 = fmaf(xd, kern[d * 1024 + 768 + hcol], z3);
        }
        float i_ = sigmoid_(z0), f_ = sigmoid_(z1), g_ = tanh_(z2), o_ = sigmoid_(z3);
        float cp = cf32[(size_t)node * 256 + hcol];
        float cc = f_ * cp + i_ * g_;
        float hc = o_ * tanh_(cc);
        HG[(size_t)node * 512 + hcol] = f2b(hc);
        CG[(size_t)node * 512 + hcol] = f2b(cc);
      }
    }
  }
}

// h_graph = tanh(S_h @ Wg + bg) (z=0) / c_graph (z=1). grid(64,4,2) x 256thr
__global__ __launch_bounds__(256) void k_graph(
    const u16* __restrict__ Sbf, const u16* __restrict__ WgTh,
    const u16* __restrict__ WgTc, const float* __restrict__ bgh,
    const float* __restrict__ bgc, u16* __restrict__ HG, u16* __restrict__ CG) {
  __shared__ __align__(16) u16 As[64 * 64];
  __shared__ __align__(16) u16 Bs[64 * 64];
  int z = blockIdx.z;
  const u16* A = Sbf + z * 256;
  const u16* WT = z ? WgTc : WgTh;
  const float* bg = z ? bgc : bgh;
  u16* outp = z ? CG : HG;
  int tid = threadIdx.x, lane = tid & 63, w = tid >> 6, wr = w >> 1, wc = w & 1;
  int m0 = blockIdx.x * 64, n0 = blockIdx.y * 64;
  f32x4 acc[2][2] = {};
  int ar = wr * 32 + (lane & 15);
  int bc = wc * 32 + (lane & 15);
  for (int kt = 0; kt < 256; kt += 64) {
    stage_tile<64, 256>(A + (size_t)m0 * 512 + kt, 512, As, tid);
    stage_tile<64, 256>(WT + (size_t)n0 * 256 + kt, 256, Bs, tid);
    __syncthreads();
#pragma unroll
    for (int kk = 0; kk < 2; ++kk) {
      int q = kk * 4 + (lane >> 4);
      bf16x8 a0 = frag_ld(As, ar, q);
      bf16x8 a1 = frag_ld(As, ar + 16, q);
      bf16x8 b0 = frag_ld(Bs, bc, q);
      bf16x8 b1 = frag_ld(Bs, bc + 16, q);
      acc[0][0] = mfma16(a0, b0, acc[0][0]);
      acc[0][1] = mfma16(a0, b1, acc[0][1]);
      acc[1][0] = mfma16(a1, b0, acc[1][0]);
      acc[1][1] = mfma16(a1, b1, acc[1][1]);
    }
    __syncthreads();
  }
#pragma unroll
  for (int m = 0; m < 2; ++m)
#pragma unroll
    for (int n = 0; n < 2; ++n)
#pragma unroll
      for (int r = 0; r < 4; ++r) {
        int row = m0 + wr * 32 + m * 16 + ((lane >> 4) << 2) + r;
        int col = n0 + wc * 32 + n * 16 + (lane & 15);
        float v = tanh_(acc[m][n][r] + bg[col]);
        outp[(size_t)row * 512 + 256 + col] = f2b(v);
      }
}

// h_upd/c_upd = sigmoid([cur|graph] @ [Wcur;Wprev] + b); z=0 also emits out_pred.
// grid(128,2) x 256thr (4 waves 1x4, BM=32, BN=256 full width)
__global__ __launch_bounds__(256) void k_merge(
    const u16* __restrict__ HG, const u16* __restrict__ CG,
    const u16* __restrict__ WhT, const u16* __restrict__ WcT,
    const float* __restrict__ bh, const float* __restrict__ bcv,
    const float* __restrict__ Wout, const float* __restrict__ bout,
    u16* __restrict__ HCrm, u16* __restrict__ HCT, float* __restrict__ cf32,
    float* __restrict__ dout, int t) {
  __shared__ __align__(16) u16 As[32 * 64];
  __shared__ __align__(16) u16 Bs[256 * 64];
  __shared__ float outacc[64];
  int z = blockIdx.y;
  const u16* Ain = z ? CG : HG;
  const u16* WT = z ? WcT : WhT;
  const float* bb = z ? bcv : bh;
  int tid = threadIdx.x, lane = tid & 63, w = tid >> 6;
  int m0 = blockIdx.x * 32;
  if (tid < 64) outacc[tid] = 0.f;
  f32x4 acc[2][4] = {};
  int ar = (lane & 15);
  int bcol = w * 64 + (lane & 15);
  for (int kt = 0; kt < 512; kt += 64) {
    stage_tile<32, 256>(Ain + (size_t)m0 * 512 + kt, 512, As, tid);
    stage_tile<256, 256>(WT + kt, 512, Bs, tid);
    __syncthreads();
#pragma unroll
    for (int kk = 0; kk < 2; ++kk) {
      int q = kk * 4 + (lane >> 4);
      bf16x8 a0 = frag_ld(As, ar, q);
      bf16x8 a1 = frag_ld(As, ar + 16, q);
      bf16x8 b0 = frag_ld(Bs, bcol, q);
      bf16x8 b1 = frag_ld(Bs, bcol + 16, q);
      bf16x8 b2 = frag_ld(Bs, bcol + 32, q);
      bf16x8 b3 = frag_ld(Bs, bcol + 48, q);
      acc[0][0] = mfma16(a0, b0, acc[0][0]);
      acc[0][1] = mfma16(a0, b1, acc[0][1]);
      acc[0][2] = mfma16(a0, b2, acc[0][2]);
      acc[0][3] = mfma16(a0, b3, acc[0][3]);
      acc[1][0] = mfma16(a1, b0, acc[1][0]);
      acc[1][1] = mfma16(a1, b1, acc[1][1]);
      acc[1][2] = mfma16(a1, b2, acc[1][2]);
      acc[1][3] = mfma16(a1, b3, acc[1][3]);
    }
    __syncthreads();
  }
#pragma unroll
  for (int m = 0; m < 2; ++m) {
#pragma unroll
    for (int r = 0; r < 4; ++r) {
      int row_local = m * 16 + ((lane >> 4) << 2) + r;
      int node = m0 + row_local;
      float p0 = 0.f, p1 = 0.f;
#pragma unroll
      for (int n = 0; n < 4; ++n) {
        int col = w * 64 + n * 16 + (lane & 15);
        float v = sigmoid_(acc[m][n][r] + bb[col]);
        if (z == 0) {
          HCrm[(size_t)node * 512 + col] = f2b(v);
          HCT[(size_t)col * 4096 + node] = f2b(v);
          p0 += v * Wout[col * 2];
          p1 += v * Wout[col * 2 + 1];
        } else {
          HCT[(size_t)(256 + col) * 4096 + node] = f2b(v);
          cf32[(size_t)node * 256 + col] = v;
        }
      }
      if (z == 0) {
#pragma unroll
        for (int off = 1; off < 16; off <<= 1) {
          p0 += __shfl_xor(p0, off);
          p1 += __shfl_xor(p1, off);
        }
        if ((lane & 15) == 0) {
          atomicAdd(&outacc[row_local * 2], p0);
          atomicAdd(&outacc[row_local * 2 + 1], p1);
        }
      }
    }
  }
  __syncthreads();
  if (z == 0 && tid < 64) {
    int row = tid >> 1, p = tid & 1;
    dout[(size_t)(m0 + row) * (NT * 2) + t * 2 + p] = outacc[tid] + bout[p];
  }
}

extern "C" void kernel_launch(void* const* d_in, const int* in_sizes, int n_in,
                              void* d_out, int out_size, void* d_ws, size_t ws_size,
                              hipStream_t stream) {
  (void)in_sizes; (void)n_in; (void)out_size; (void)ws_size;
  const float* inputs = (const float*)d_in[0];
  const float* A      = (const float*)d_in[1];
  const float* kern   = (const float*)d_in[2];
  const float* rk     = (const float*)d_in[3];
  const float* lbias  = (const float*)d_in[4];
  const float* wgh    = (const float*)d_in[5];
  const float* bgh    = (const float*)d_in[6];
  const float* wgc    = (const float*)d_in[7];
  const float* bgc    = (const float*)d_in[8];
  const float* whc    = (const float*)d_in[9];
  const float* whp    = (const float*)d_in[10];
  const float* bh     = (const float*)d_in[11];
  const float* wcc    = (const float*)d_in[12];
  const float* wcp    = (const float*)d_in[13];
  const float* bcv    = (const float*)d_in[14];
  const float* wout   = (const float*)d_in[15];
  const float* bout   = (const float*)d_in[16];
  float* dout = (float*)d_out;

  char* p = (char*)d_ws;
  u16* Abf  = (u16*)p; p += (size_t)4096 * 4096 * 2;   // 33.55 MB
  u16* HCrm = (u16*)p; p += (size_t)4096 * 512 * 2;    // [h|c] row-major bf16
  u16* HCT  = (u16*)p; p += (size_t)4096 * 512 * 2;    // [512][4096] transposed
  float* cf32 = (float*)p; p += (size_t)4096 * 256 * 4;
  u16* Sbf  = (u16*)p; p += (size_t)4096 * 512 * 2;
  u16* HG   = (u16*)p; p += (size_t)4096 * 512 * 2;    // [h_cur|h_graph]
  u16* CG   = (u16*)p; p += (size_t)4096 * 512 * 2;    // [c_cur|c_graph]
  u16* rkT  = (u16*)p; p += (size_t)1024 * 256 * 2;
  u16* WgThp = (u16*)p; p += (size_t)65536 * 2;
  u16* WgTcp = (u16*)p; p += (size_t)65536 * 2;
  u16* WhTp  = (u16*)p; p += (size_t)131072 * 2;
  u16* WcTp  = (u16*)p; p += (size_t)131072 * 2;

  k_convA<<<8192, 256, 0, stream>>>(A, Abf);
  // zero HCrm + HCT + cf32 (contiguous, 12.58 MB)
  k_zero<<<3072, 256, 0, stream>>>((float4*)HCrm);
  k_prep<<<2560, 256, 0, stream>>>(rk, wgh, wgc, whc, whp, wcc, wcp,
                                   rkT, WgThp, WgTcp, WhTp, WcTp);

  for (int t = 0; t < NT; ++t) {
    k_big<<<dim3(32, 8), 512, 0, stream>>>(Abf, HCT, Sbf);
    k_gates<<<dim3(64, 4), 256, 0, stream>>>(HCrm, rkT, cf32, inputs, kern, lbias,
                                             HG, CG, t);
    k_graph<<<dim3(64, 4, 2), 256, 0, stream>>>(Sbf, WgThp, WgTcp, bgh, bgc, HG, CG);
    k_merge<<<dim3(128, 2), 256, 0, stream>>>(HG, CG, WhTp, WcTp, bh, bcv, wout, bout,
                                              HCrm, HCT, cf32, dout, t);
  }
}

// Round 2
// 24181.766 us; speedup vs baseline: 1.5365x; 1.5365x over previous
//
#include <hip/hip_runtime.h>
#include <hip/hip_bf16.h>
#include <stdint.h>

typedef unsigned short u16;
typedef __bf16 bf16x8 __attribute__((ext_vector_type(8)));
typedef float f32x4 __attribute__((ext_vector_type(4)));

#define NT 365
#define NNODE 4096

__device__ __forceinline__ u16 f2b(float f) {
  __bf16 b = (__bf16)f;
  return __builtin_bit_cast(u16, b);
}
__device__ __forceinline__ float sigmoid_(float x) { return 1.f / (1.f + __expf(-x)); }
__device__ __forceinline__ float tanh_(float x) {
  float ax = fabsf(x);
  float e = __expf(-2.f * ax);
  float r = (1.f - e) / (1.f + e);
  return copysignf(r, x);
}

__device__ __forceinline__ void gload_lds16(const void* g, void* l) {
  __builtin_amdgcn_global_load_lds((const __attribute__((address_space(1))) void*)g,
                                   (__attribute__((address_space(3))) void*)l, 16, 0, 0);
}

// Stage RT rows x 64 bf16 cols into LDS. LDS dest linear (global_load_lds
// requirement); k-chunk XOR-swizzled on the GLOBAL source so the swizzled
// ds_read_b128 (frag_ld) is bank-conflict-free. gstride in elements.
template <int RT, int NTH>
__device__ __forceinline__ void stage_tile(const u16* __restrict__ g, int gstride,
                                           u16* lds, int tid) {
  constexpr int ITERS = (RT * 128) / (NTH * 16);
#pragma unroll
  for (int i = 0; i < ITERS; ++i) {
    int slot = i * NTH + tid;
    int off = slot << 4;               // LDS byte offset (linear)
    int row = off >> 7;                // 128 B per row (64 bf16)
    int k8 = ((off >> 4) & 7) ^ (row & 7);
    gload_lds16((const char*)(g + (size_t)row * gstride) + (k8 << 4), (char*)lds + off);
  }
}

// read 8 contiguous bf16 (one 16B chunk) for MFMA A/B fragment, undoing swizzle
__device__ __forceinline__ bf16x8 frag_ld(const u16* lds, int row, int q) {
  int off = (row << 7) + ((q ^ (row & 7)) << 4);
  return *(const bf16x8*)((const char*)lds + off);
}

__device__ __forceinline__ f32x4 mfma16(bf16x8 a, bf16x8 b, f32x4 c) {
  return __builtin_amdgcn_mfma_f32_16x16x32_bf16(a, b, c, 0, 0, 0);
}

// ---------------- init kernels ----------------

__global__ void k_convA(const float* __restrict__ A, u16* __restrict__ Abf) {
  size_t i = ((size_t)blockIdx.x * 256 + threadIdx.x) * 8;
  float4 v0 = *(const float4*)(A + i);
  float4 v1 = *(const float4*)(A + i + 4);
  union { u16 u[8]; uint4 q; } o;
  o.u[0] = f2b(v0.x); o.u[1] = f2b(v0.y); o.u[2] = f2b(v0.z); o.u[3] = f2b(v0.w);
  o.u[4] = f2b(v1.x); o.u[5] = f2b(v1.y); o.u[6] = f2b(v1.z); o.u[7] = f2b(v1.w);
  *(uint4*)(Abf + i) = o.q;
}

__global__ void k_zero(float4* __restrict__ p) {
  p[(size_t)blockIdx.x * 256 + threadIdx.x] = make_float4(0.f, 0.f, 0.f, 0.f);
}

// x_0 into HX augmented cols [256,272)
__global__ void k_x0(const float* __restrict__ x, u16* __restrict__ HX) {
  int i = blockIdx.x * 256 + threadIdx.x;  // 65536
  int node = i >> 4, d = i & 15;
  HX[(size_t)node * 320 + 256 + d] = f2b(x[(size_t)node * (NT * 16) + d]);
}

// transpose+convert weights to bf16 B^T layouts. rkTa [1024][320] augmented:
// cols 0..255 = rkernel^T, 256..271 = kernel^T, 272..319 = 0.
__global__ void k_prep(const float* __restrict__ rk, const float* __restrict__ kern,
                       const float* __restrict__ wgh, const float* __restrict__ wgc,
                       const float* __restrict__ whc, const float* __restrict__ whp,
                       const float* __restrict__ wcc, const float* __restrict__ wcp,
                       u16* __restrict__ rkTa, u16* __restrict__ WgTh,
                       u16* __restrict__ WgTc, u16* __restrict__ WhT,
                       u16* __restrict__ WcT) {
  int i = blockIdx.x * 256 + threadIdx.x;
  if (i < 327680) {
    int j = i / 320, k = i % 320;
    float v = k < 256 ? rk[(size_t)k * 1024 + j]
                      : (k < 272 ? kern[(size_t)(k - 256) * 1024 + j] : 0.f);
    rkTa[i] = f2b(v);
    return;
  }
  i -= 327680;
  if (i < 65536) { int j = i >> 8, k = i & 255; WgTh[i] = f2b(wgh[k * 256 + j]); return; }
  i -= 65536;
  if (i < 65536) { int j = i >> 8, k = i & 255; WgTc[i] = f2b(wgc[k * 256 + j]); return; }
  i -= 65536;
  if (i < 131072) {
    int j = i >> 9, k = i & 511;
    WhT[i] = f2b(k < 256 ? whc[k * 256 + j] : whp[(k - 256) * 256 + j]);
    return;
  }
  i -= 131072;
  if (i < 131072) {
    int j = i >> 9, k = i & 511;
    WcT[i] = f2b(k < 256 ? wcc[k * 256 + j] : wcp[(k - 256) * 256 + j]);
  }
}

// ---------------- per-step kernels ----------------

// Sp[z] += A[4096][4096] @ HC over K-range z. 128x128 tile, 4 waves of 64x64,
// 2-phase LDS double-buffer. grid(32,4,nsplit) x 256thr.
__global__ __launch_bounds__(256) void k_big(const u16* __restrict__ Abf,
                                             const u16* __restrict__ HCT,
                                             float* __restrict__ Sp, int kspan) {
  __shared__ __align__(16) u16 As[2][128 * 64];
  __shared__ __align__(16) u16 Bs[2][128 * 64];
  int tid = threadIdx.x, lane = tid & 63, w = tid >> 6;
  int wr = w >> 1, wc = w & 1;
  int m0 = blockIdx.x * 128, n0 = blockIdx.y * 128;
  int k0 = blockIdx.z * kspan;
  f32x4 acc[4][4] = {};
  int ar = wr * 64 + (lane & 15);
  int bc = wc * 64 + (lane & 15);
  int nk = kspan >> 6;
  stage_tile<128, 256>(Abf + (size_t)m0 * 4096 + k0, 4096, As[0], tid);
  stage_tile<128, 256>(HCT + (size_t)n0 * 4096 + k0, 4096, Bs[0], tid);
  __syncthreads();
  for (int kt = 0; kt < nk; ++kt) {
    int cb = kt & 1;
    if (kt + 1 < nk) {
      stage_tile<128, 256>(Abf + (size_t)m0 * 4096 + k0 + (kt + 1) * 64, 4096,
                           As[cb ^ 1], tid);
      stage_tile<128, 256>(HCT + (size_t)n0 * 4096 + k0 + (kt + 1) * 64, 4096,
                           Bs[cb ^ 1], tid);
    }
#pragma unroll
    for (int kk = 0; kk < 2; ++kk) {
      int q = kk * 4 + (lane >> 4);
      bf16x8 a[4], b[4];
#pragma unroll
      for (int m = 0; m < 4; ++m) a[m] = frag_ld(As[cb], ar + m * 16, q);
#pragma unroll
      for (int n = 0; n < 4; ++n) b[n] = frag_ld(Bs[cb], bc + n * 16, q);
#pragma unroll
      for (int m = 0; m < 4; ++m)
#pragma unroll
        for (int n = 0; n < 4; ++n) acc[m][n] = mfma16(a[m], b[n], acc[m][n]);
    }
    __syncthreads();
  }
  float* Spz = Sp + (size_t)blockIdx.z * (4096 * 512);
#pragma unroll
  for (int m = 0; m < 4; ++m)
#pragma unroll
    for (int n = 0; n < 4; ++n)
#pragma unroll
      for (int r = 0; r < 4; ++r) {
        int row = m0 + wr * 64 + m * 16 + ((lane >> 4) << 2) + r;
        int col = n0 + wc * 64 + n * 16 + (lane & 15);
        Spz[(size_t)row * 512 + col] = acc[m][n][r];
      }
}

// Sbf = bf16(sum of nsplit partials). grid 2048 x 256.
__global__ void k_red(const float* __restrict__ Sp, u16* __restrict__ Sbf, int nsplit) {
  size_t i = (size_t)blockIdx.x * 256 + threadIdx.x;
  const f32x4* p = (const f32x4*)Sp;
  f32x4 s = p[i];
  for (int z = 1; z < nsplit; ++z) s += p[(size_t)z * 524288 + i];
  union { u16 u[4]; uint2 q; } o;
  o.u[0] = f2b(s[0]); o.u[1] = f2b(s[1]); o.u[2] = f2b(s[2]); o.u[3] = f2b(s[3]);
  ((uint2*)Sbf)[i] = o.q;
}

// Fused gates (z=0, augmented K=320) + graph h/c (z=1/2). grid(64,4,3) x 256thr.
__global__ __launch_bounds__(256) void k_mid(
    const u16* __restrict__ HX, const u16* __restrict__ rkTa,
    const float* __restrict__ cf32, const float* __restrict__ lbias,
    const u16* __restrict__ Sbf, const u16* __restrict__ WgTh,
    const u16* __restrict__ WgTc, const float* __restrict__ bgh,
    const float* __restrict__ bgc, u16* __restrict__ HG, u16* __restrict__ CG) {
  __shared__ __align__(16) u16 As[64 * 64];
  __shared__ __align__(16) u16 Bs[4 * 64 * 64];
  int tid = threadIdx.x, lane = tid & 63, w = tid >> 6, wr = w >> 1, wc = w & 1;
  int z = blockIdx.z;
  int m0 = blockIdx.x * 64, c0 = blockIdx.y * 64;
  int ar = wr * 32 + (lane & 15);
  int bc = wc * 32 + (lane & 15);
  if (z == 0) {
    f32x4 acc[4][2][2] = {};
    for (int kt = 0; kt < 320; kt += 64) {
      stage_tile<64, 256>(HX + (size_t)m0 * 320 + kt, 320, As, tid);
#pragma unroll
      for (int i = 0; i < 8; ++i) {  // 4 gate segments x 64 rows of rkTa
        int slot = i * 256 + tid;
        int off = slot << 4;
        int row = off >> 7;
        int k8 = ((off >> 4) & 7) ^ (row & 7);
        int grow = ((row >> 6) << 8) + c0 + (row & 63);
        gload_lds16((const char*)(rkTa + (size_t)grow * 320 + kt) + (k8 << 4),
                    (char*)Bs + off);
      }
      __syncthreads();
#pragma unroll
      for (int kk = 0; kk < 2; ++kk) {
        int q = kk * 4 + (lane >> 4);
        bf16x8 a0 = frag_ld(As, ar, q);
        bf16x8 a1 = frag_ld(As, ar + 16, q);
#pragma unroll
        for (int s = 0; s < 4; ++s) {
          const u16* B = Bs + s * 4096;
          bf16x8 b0 = frag_ld(B, bc, q);
          bf16x8 b1 = frag_ld(B, bc + 16, q);
          acc[s][0][0] = mfma16(a0, b0, acc[s][0][0]);
          acc[s][0][1] = mfma16(a0, b1, acc[s][0][1]);
          acc[s][1][0] = mfma16(a1, b0, acc[s][1][0]);
          acc[s][1][1] = mfma16(a1, b1, acc[s][1][1]);
        }
      }
      __syncthreads();
    }
#pragma unroll
    for (int m = 0; m < 2; ++m)
#pragma unroll
      for (int r = 0; r < 4; ++r) {
        int node = m0 + wr * 32 + m * 16 + ((lane >> 4) << 2) + r;
#pragma unroll
        for (int n = 0; n < 2; ++n) {
          int hcol = c0 + wc * 32 + n * 16 + (lane & 15);
          float z0 = acc[0][m][n][r] + lbias[hcol];
          float z1 = acc[1][m][n][r] + lbias[256 + hcol];
          float z2 = acc[2][m][n][r] + lbias[512 + hcol];
          float z3 = acc[3][m][n][r] + lbias[768 + hcol];
          float i_ = sigmoid_(z0), f_ = sigmoid_(z1);
          float g_ = tanh_(z2), o_ = sigmoid_(z3);
          float cp = cf32[(size_t)node * 256 + hcol];
          float cc = f_ * cp + i_ * g_;
          float hc = o_ * tanh_(cc);
          HG[(size_t)node * 512 + hcol] = f2b(hc);
          CG[(size_t)node * 512 + hcol] = f2b(cc);
        }
      }
  } else {
    const u16* Ain = Sbf + (z - 1) * 256;
    const u16* WT = (z == 2) ? WgTc : WgTh;
    const float* bg = (z == 2) ? bgc : bgh;
    u16* outp = (z == 2) ? CG : HG;
    f32x4 acc[2][2] = {};
    for (int kt = 0; kt < 256; kt += 64) {
      stage_tile<64, 256>(Ain + (size_t)m0 * 512 + kt, 512, As, tid);
      stage_tile<64, 256>(WT + (size_t)c0 * 256 + kt, 256, Bs, tid);
      __syncthreads();
#pragma unroll
      for (int kk = 0; kk < 2; ++kk) {
        int q = kk * 4 + (lane >> 4);
        bf16x8 a0 = frag_ld(As, ar, q);
        bf16x8 a1 = frag_ld(As, ar + 16, q);
        bf16x8 b0 = frag_ld(Bs, bc, q);
        bf16x8 b1 = frag_ld(Bs, bc + 16, q);
        acc[0][0] = mfma16(a0, b0, acc[0][0]);
        acc[0][1] = mfma16(a0, b1, acc[0][1]);
        acc[1][0] = mfma16(a1, b0, acc[1][0]);
        acc[1][1] = mfma16(a1, b1, acc[1][1]);
      }
      __syncthreads();
    }
#pragma unroll
    for (int m = 0; m < 2; ++m)
#pragma unroll
      for (int n = 0; n < 2; ++n)
#pragma unroll
        for (int r = 0; r < 4; ++r) {
          int row = m0 + wr * 32 + m * 16 + ((lane >> 4) << 2) + r;
          int col = c0 + wc * 32 + n * 16 + (lane & 15);
          float v = tanh_(acc[m][n][r] + bg[col]);
          outp[(size_t)row * 512 + 256 + col] = f2b(v);
        }
  }
}

// h_upd/c_upd = sigmoid([cur|graph] @ [Wcur;Wprev] + b); z=0 emits out_pred and
// writes HX h-cols + x_{t+1}; z=1 writes cf32. grid(128,2) x 256thr.
__global__ __launch_bounds__(256) void k_merge(
    const u16* __restrict__ HG, const u16* __restrict__ CG,
    const u16* __restrict__ WhT, const u16* __restrict__ WcT,
    const float* __restrict__ bh, const float* __restrict__ bcv,
    const float* __restrict__ Wout, const float* __restrict__ bout,
    u16* __restrict__ HX, u16* __restrict__ HCT, float* __restrict__ cf32,
    float* __restrict__ dout, const float* __restrict__ xin, int t) {
  __shared__ __align__(16) u16 As[32 * 64];
  __shared__ __align__(16) u16 Bs[256 * 64];
  __shared__ float outacc[64];
  int z = blockIdx.y;
  const u16* Ain = z ? CG : HG;
  const u16* WT = z ? WcT : WhT;
  const float* bb = z ? bcv : bh;
  int tid = threadIdx.x, lane = tid & 63, w = tid >> 6;
  int m0 = blockIdx.x * 32;
  if (tid < 64) outacc[tid] = 0.f;
  f32x4 acc[2][4] = {};
  int ar = (lane & 15);
  int bcol = w * 64 + (lane & 15);
  for (int kt = 0; kt < 512; kt += 64) {
    stage_tile<32, 256>(Ain + (size_t)m0 * 512 + kt, 512, As, tid);
    stage_tile<256, 256>(WT + kt, 512, Bs, tid);
    __syncthreads();
#pragma unroll
    for (int kk = 0; kk < 2; ++kk) {
      int q = kk * 4 + (lane >> 4);
      bf16x8 a0 = frag_ld(As, ar, q);
      bf16x8 a1 = frag_ld(As, ar + 16, q);
      bf16x8 b0 = frag_ld(Bs, bcol, q);
      bf16x8 b1 = frag_ld(Bs, bcol + 16, q);
      bf16x8 b2 = frag_ld(Bs, bcol + 32, q);
      bf16x8 b3 = frag_ld(Bs, bcol + 48, q);
      acc[0][0] = mfma16(a0, b0, acc[0][0]);
      acc[0][1] = mfma16(a0, b1, acc[0][1]);
      acc[0][2] = mfma16(a0, b2, acc[0][2]);
      acc[0][3] = mfma16(a0, b3, acc[0][3]);
      acc[1][0] = mfma16(a1, b0, acc[1][0]);
      acc[1][1] = mfma16(a1, b1, acc[1][1]);
      acc[1][2] = mfma16(a1, b2, acc[1][2]);
      acc[1][3] = mfma16(a1, b3, acc[1][3]);
    }
    __syncthreads();
  }
#pragma unroll
  for (int m = 0; m < 2; ++m) {
#pragma unroll
    for (int r = 0; r < 4; ++r) {
      int row_local = m * 16 + ((lane >> 4) << 2) + r;
      int node = m0 + row_local;
      float p0 = 0.f, p1 = 0.f;
#pragma unroll
      for (int n = 0; n < 4; ++n) {
        int col = w * 64 + n * 16 + (lane & 15);
        float v = sigmoid_(acc[m][n][r] + bb[col]);
        if (z == 0) {
          HX[(size_t)node * 320 + col] = f2b(v);
          HCT[(size_t)col * 4096 + node] = f2b(v);
          p0 += v * Wout[col * 2];
          p1 += v * Wout[col * 2 + 1];
        } else {
          HCT[(size_t)(256 + col) * 4096 + node] = f2b(v);
          cf32[(size_t)node * 256 + col] = v;
        }
      }
      if (z == 0) {
#pragma unroll
        for (int off = 1; off < 16; off <<= 1) {
          p0 += __shfl_xor(p0, off);
          p1 += __shfl_xor(p1, off);
        }
        if ((lane & 15) == 0) {
          atomicAdd(&outacc[row_local * 2], p0);
          atomicAdd(&outacc[row_local * 2 + 1], p1);
        }
      }
    }
  }
  if (z == 0 && t + 1 < NT) {
    for (int i = tid; i < 512; i += 256) {
      int node = m0 + (i >> 4), d = i & 15;
      HX[(size_t)node * 320 + 256 + d] =
          f2b(xin[(size_t)node * (NT * 16) + (t + 1) * 16 + d]);
    }
  }
  __syncthreads();
  if (z == 0 && tid < 64) {
    int row = tid >> 1, p = tid & 1;
    dout[(size_t)(m0 + row) * (NT * 2) + t * 2 + p] = outacc[tid] + bout[p];
  }
}

extern "C" void kernel_launch(void* const* d_in, const int* in_sizes, int n_in,
                              void* d_out, int out_size, void* d_ws, size_t ws_size,
                              hipStream_t stream) {
  (void)in_sizes; (void)n_in; (void)out_size;
  const float* inputs = (const float*)d_in[0];
  const float* A      = (const float*)d_in[1];
  const float* kern   = (const float*)d_in[2];
  const float* rk     = (const float*)d_in[3];
  const float* lbias  = (const float*)d_in[4];
  const float* wgh    = (const float*)d_in[5];
  const float* bgh    = (const float*)d_in[6];
  const float* wgc    = (const float*)d_in[7];
  const float* bgc    = (const float*)d_in[8];
  const float* whc    = (const float*)d_in[9];
  const float* whp    = (const float*)d_in[10];
  const float* bh     = (const float*)d_in[11];
  const float* wcc    = (const float*)d_in[12];
  const float* wcp    = (const float*)d_in[13];
  const float* bcv    = (const float*)d_in[14];
  const float* wout   = (const float*)d_in[15];
  const float* bout   = (const float*)d_in[16];
  float* dout = (float*)d_out;

  int nsplit = ws_size >= 93000000 ? 4 : (ws_size >= 76000000 ? 2 : 1);
  int kspan = 4096 / nsplit;

  char* p = (char*)d_ws;
  u16* Abf  = (u16*)p; p += (size_t)4096 * 4096 * 2;   // 33.55 MB
  u16* HX   = (u16*)p; p += (size_t)4096 * 320 * 2;    // [h(256)|x(16)|0(48)]
  u16* HCT  = (u16*)p; p += (size_t)4096 * 512 * 2;    // [512][4096] transposed
  float* cf32 = (float*)p; p += (size_t)4096 * 256 * 4;
  float* Sp = (float*)p; p += (size_t)nsplit * 4096 * 512 * 4;
  u16* Sbf  = (u16*)p; p += (size_t)4096 * 512 * 2;
  u16* HG   = (u16*)p; p += (size_t)4096 * 512 * 2;    // [h_cur|h_graph]
  u16* CG   = (u16*)p; p += (size_t)4096 * 512 * 2;    // [c_cur|c_graph]
  u16* rkTa = (u16*)p; p += (size_t)1024 * 320 * 2;    // augmented [rk;kern;0]
  u16* WgThp = (u16*)p; p += (size_t)65536 * 2;
  u16* WgTcp = (u16*)p; p += (size_t)65536 * 2;
  u16* WhTp  = (u16*)p; p += (size_t)131072 * 2;
  u16* WcTp  = (u16*)p; p += (size_t)131072 * 2;

  k_convA<<<8192, 256, 0, stream>>>(A, Abf);
  // zero HX + HCT + cf32 (contiguous, 11,010,048 B = 688,128 float4)
  k_zero<<<2688, 256, 0, stream>>>((float4*)HX);
  k_x0<<<256, 256, 0, stream>>>(inputs, HX);
  k_prep<<<2816, 256, 0, stream>>>(rk, kern, wgh, wgc, whc, whp, wcc, wcp,
                                   rkTa, WgThp, WgTcp, WhTp, WcTp);

  for (int t = 0; t < NT; ++t) {
    k_big<<<dim3(32, 4, nsplit), 256, 0, stream>>>(Abf, HCT, Sp, kspan);
    k_red<<<2048, 256, 0, stream>>>(Sp, Sbf, nsplit);
    k_mid<<<dim3(64, 4, 3), 256, 0, stream>>>(HX, rkTa, cf32, lbias, Sbf,
                                              WgThp, WgTcp, bgh, bgc, HG, CG);
    k_merge<<<dim3(128, 2), 256, 0, stream>>>(HG, CG, WhTp, WcTp, bh, bcv, wout,
                                              bout, HX, HCT, cf32, dout, inputs, t);
  }
}

// Round 3
// 22565.546 us; speedup vs baseline: 1.6465x; 1.0716x over previous
//
#include <hip/hip_runtime.h>
#include <hip/hip_bf16.h>
#include <stdint.h>

typedef unsigned short u16;
typedef __bf16 bf16x8 __attribute__((ext_vector_type(8)));
typedef float f32x4 __attribute__((ext_vector_type(4)));

#define NT 365
#define NNODE 4096

__device__ __forceinline__ u16 f2b(float f) {
  __bf16 b = (__bf16)f;
  return __builtin_bit_cast(u16, b);
}
__device__ __forceinline__ float sigmoid_(float x) { return 1.f / (1.f + __expf(-x)); }
__device__ __forceinline__ float tanh_(float x) {
  float ax = fabsf(x);
  float e = __expf(-2.f * ax);
  float r = (1.f - e) / (1.f + e);
  return copysignf(r, x);
}

__device__ __forceinline__ void gload_lds16(const void* g, void* l) {
  __builtin_amdgcn_global_load_lds((const __attribute__((address_space(1))) void*)g,
                                   (__attribute__((address_space(3))) void*)l, 16, 0, 0);
}

// Stage RT rows x 64 bf16 cols into LDS. LDS dest linear (global_load_lds
// requirement); k-chunk XOR-swizzled on the GLOBAL source so the swizzled
// ds_read_b128 (frag_ld) is bank-conflict-free. gstride in elements.
template <int RT, int NTH>
__device__ __forceinline__ void stage_tile(const u16* __restrict__ g, int gstride,
                                           u16* lds, int tid) {
  constexpr int ITERS = (RT * 128) / (NTH * 16);
#pragma unroll
  for (int i = 0; i < ITERS; ++i) {
    int slot = i * NTH + tid;
    int off = slot << 4;               // LDS byte offset (linear)
    int row = off >> 7;                // 128 B per row (64 bf16)
    int k8 = ((off >> 4) & 7) ^ (row & 7);
    gload_lds16((const char*)(g + (size_t)row * gstride) + (k8 << 4), (char*)lds + off);
  }
}

// read 8 contiguous bf16 (one 16B chunk) for MFMA A/B fragment, undoing swizzle
__device__ __forceinline__ bf16x8 frag_ld(const u16* lds, int row, int q) {
  int off = (row << 7) + ((q ^ (row & 7)) << 4);
  return *(const bf16x8*)((const char*)lds + off);
}

__device__ __forceinline__ f32x4 mfma16(bf16x8 a, bf16x8 b, f32x4 c) {
  return __builtin_amdgcn_mfma_f32_16x16x32_bf16(a, b, c, 0, 0, 0);
}

// accumulate 8 bf16 (packed in uint4) into f[8] as f32
__device__ __forceinline__ void acc8(uint4 v, float* f) {
  f[0] += __builtin_bit_cast(float, v.x << 16);
  f[1] += __builtin_bit_cast(float, v.x & 0xffff0000u);
  f[2] += __builtin_bit_cast(float, v.y << 16);
  f[3] += __builtin_bit_cast(float, v.y & 0xffff0000u);
  f[4] += __builtin_bit_cast(float, v.z << 16);
  f[5] += __builtin_bit_cast(float, v.z & 0xffff0000u);
  f[6] += __builtin_bit_cast(float, v.w << 16);
  f[7] += __builtin_bit_cast(float, v.w & 0xffff0000u);
}

// ---------------- init kernels ----------------

__global__ void k_convA(const float* __restrict__ A, u16* __restrict__ Abf) {
  size_t i = ((size_t)blockIdx.x * 256 + threadIdx.x) * 8;
  float4 v0 = *(const float4*)(A + i);
  float4 v1 = *(const float4*)(A + i + 4);
  union { u16 u[8]; uint4 q; } o;
  o.u[0] = f2b(v0.x); o.u[1] = f2b(v0.y); o.u[2] = f2b(v0.z); o.u[3] = f2b(v0.w);
  o.u[4] = f2b(v1.x); o.u[5] = f2b(v1.y); o.u[6] = f2b(v1.z); o.u[7] = f2b(v1.w);
  *(uint4*)(Abf + i) = o.q;
}

__global__ void k_zero(float4* __restrict__ p) {
  p[(size_t)blockIdx.x * 256 + threadIdx.x] = make_float4(0.f, 0.f, 0.f, 0.f);
}

// x_0 into HX augmented cols [256,272)
__global__ void k_x0(const float* __restrict__ x, u16* __restrict__ HX) {
  int i = blockIdx.x * 256 + threadIdx.x;  // 65536
  int node = i >> 4, d = i & 15;
  HX[(size_t)node * 320 + 256 + d] = f2b(x[(size_t)node * (NT * 16) + d]);
}

// transpose+convert weights to bf16 B^T layouts. rkTa [1024][320] augmented:
// cols 0..255 = rkernel^T, 256..271 = kernel^T, 272..319 = 0.
__global__ void k_prep(const float* __restrict__ rk, const float* __restrict__ kern,
                       const float* __restrict__ wgh, const float* __restrict__ wgc,
                       const float* __restrict__ whc, const float* __restrict__ whp,
                       const float* __restrict__ wcc, const float* __restrict__ wcp,
                       u16* __restrict__ rkTa, u16* __restrict__ WgTh,
                       u16* __restrict__ WgTc, u16* __restrict__ WhT,
                       u16* __restrict__ WcT) {
  int i = blockIdx.x * 256 + threadIdx.x;
  if (i < 327680) {
    int j = i / 320, k = i % 320;
    float v = k < 256 ? rk[(size_t)k * 1024 + j]
                      : (k < 272 ? kern[(size_t)(k - 256) * 1024 + j] : 0.f);
    rkTa[i] = f2b(v);
    return;
  }
  i -= 327680;
  if (i < 65536) { int j = i >> 8, k = i & 255; WgTh[i] = f2b(wgh[k * 256 + j]); return; }
  i -= 65536;
  if (i < 65536) { int j = i >> 8, k = i & 255; WgTc[i] = f2b(wgc[k * 256 + j]); return; }
  i -= 65536;
  if (i < 131072) {
    int j = i >> 9, k = i & 511;
    WhT[i] = f2b(k < 256 ? whc[k * 256 + j] : whp[(k - 256) * 256 + j]);
    return;
  }
  i -= 131072;
  if (i < 131072) {
    int j = i >> 9, k = i & 511;
    WcT[i] = f2b(k < 256 ? wcc[k * 256 + j] : wcp[(k - 256) * 256 + j]);
  }
}

// ---------------- per-step kernels ----------------

// L1: Spb[s] = A[4096][4096] @ HC over K-range s, bf16 partials.
// 128x128 tile, 4 waves of 64x64, 2-phase LDS double-buffer.
// grid 128*nsplit blocks x 256thr, XCD-aware bid decode.
__global__ __launch_bounds__(256) void k_big(const u16* __restrict__ Abf,
                                             const u16* __restrict__ HCT,
                                             u16* __restrict__ Spb, int nsplit) {
  __shared__ __align__(16) u16 As[2][128 * 64];
  __shared__ __align__(16) u16 Bs[2][128 * 64];
  int bid = blockIdx.x;
  int mb, nb, sb;
  if (nsplit == 4) {
    // bid = (m>>4) | s<<1 | (m&15)<<3 | n<<7 ; XCD (= bid&7) pins (m-half, s):
    // each XCD's 64 co-resident blocks share a 4MB A-slice + 1MB B-slice (L2-fit)
    int mhi = bid & 1, sp = (bid >> 1) & 3, rest = bid >> 3;
    mb = mhi * 16 + (rest & 15); nb = rest >> 4; sb = sp;
  } else {  // nsplit == 2, 256 blocks
    mb = bid & 31; nb = (bid >> 5) & 3; sb = bid >> 7;
  }
  int kspan = 4096 / nsplit;
  int tid = threadIdx.x, lane = tid & 63, w = tid >> 6;
  int wr = w >> 1, wc = w & 1;
  int m0 = mb * 128, n0 = nb * 128, k0 = sb * kspan;
  f32x4 acc[4][4] = {};
  int ar = wr * 64 + (lane & 15);
  int bc = wc * 64 + (lane & 15);
  int nk = kspan >> 6;
  stage_tile<128, 256>(Abf + (size_t)m0 * 4096 + k0, 4096, As[0], tid);
  stage_tile<128, 256>(HCT + (size_t)n0 * 4096 + k0, 4096, Bs[0], tid);
  __syncthreads();
  for (int kt = 0; kt < nk; ++kt) {
    int cb = kt & 1;
    if (kt + 1 < nk) {
      stage_tile<128, 256>(Abf + (size_t)m0 * 4096 + k0 + (kt + 1) * 64, 4096,
                           As[cb ^ 1], tid);
      stage_tile<128, 256>(HCT + (size_t)n0 * 4096 + k0 + (kt + 1) * 64, 4096,
                           Bs[cb ^ 1], tid);
    }
#pragma unroll
    for (int kk = 0; kk < 2; ++kk) {
      int q = kk * 4 + (lane >> 4);
      bf16x8 a[4], b[4];
#pragma unroll
      for (int m = 0; m < 4; ++m) a[m] = frag_ld(As[cb], ar + m * 16, q);
#pragma unroll
      for (int n = 0; n < 4; ++n) b[n] = frag_ld(Bs[cb], bc + n * 16, q);
#pragma unroll
      for (int m = 0; m < 4; ++m)
#pragma unroll
        for (int n = 0; n < 4; ++n) acc[m][n] = mfma16(a[m], b[n], acc[m][n]);
    }
    __syncthreads();
  }
  u16* out = Spb + (size_t)sb * (4096 * 512);
#pragma unroll
  for (int m = 0; m < 4; ++m)
#pragma unroll
    for (int n = 0; n < 4; ++n)
#pragma unroll
      for (int r = 0; r < 4; ++r) {
        int row = m0 + wr * 64 + m * 16 + ((lane >> 4) << 2) + r;
        int col = n0 + wc * 64 + n * 16 + (lane & 15);
        out[(size_t)row * 512 + col] = f2b(acc[m][n][r]);
      }
}

// L2 hetero: bid<512 -> graph GEMM (split-K reduce fused into A-staging);
//            bid>=512 -> LSTM gates (augmented K=320). 768 blocks x 256thr.
__global__ __launch_bounds__(256) void k_phase2(
    const u16* __restrict__ Spb, int nsplit, const u16* __restrict__ HX,
    const u16* __restrict__ rkTa, const float* __restrict__ cf32,
    const float* __restrict__ lbias, const u16* __restrict__ WgTh,
    const u16* __restrict__ WgTc, const float* __restrict__ bgh,
    const float* __restrict__ bgc, u16* __restrict__ HG, u16* __restrict__ CG) {
  __shared__ __align__(16) u16 As[64 * 64];
  __shared__ __align__(16) u16 Bs[4 * 64 * 64];
  int bid = blockIdx.x;
  int tid = threadIdx.x, lane = tid & 63, w = tid >> 6, wr = w >> 1, wc = w & 1;
  int ar = wr * 32 + (lane & 15);
  int bc = wc * 32 + (lane & 15);
  if (bid < 512) {
    // ---- graph: out = tanh(S_half @ Wg + bg) ----
    int zz = bid >> 8;                    // 0: h-half, 1: c-half
    int c0 = ((bid >> 6) & 3) * 64;
    int m0 = (bid & 63) * 64;
    const u16* WT = zz ? WgTc : WgTh;
    const float* bg = zz ? bgc : bgh;
    u16* outp = zz ? CG : HG;
    f32x4 acc[2][2] = {};
    for (int kt = 0; kt < 256; kt += 64) {
      // A-stage: reduce nsplit bf16 partials -> bf16, swizzled ds_write
#pragma unroll
      for (int j = 0; j < 2; ++j) {
        int ch = j * 256 + tid;           // chunk: 8 bf16 = 16B
        int srow = ch >> 3, sq = ch & 7;
        const u16* gsrc = Spb + (size_t)(m0 + srow) * 512 + zz * 256 + kt + sq * 8;
        float f[8] = {};
        for (int s = 0; s < nsplit; ++s)
          acc8(*(const uint4*)(gsrc + (size_t)s * (4096 * 512)), f);
        union { u16 u[8]; uint4 q; } o;
#pragma unroll
        for (int e = 0; e < 8; ++e) o.u[e] = f2b(f[e]);
        int slot = sq ^ (srow & 7);
        *(uint4*)((char*)As + (srow << 7) + (slot << 4)) = o.q;
      }
      stage_tile<64, 256>(WT + (size_t)c0 * 256 + kt, 256, Bs, tid);
      __syncthreads();
#pragma unroll
      for (int kk = 0; kk < 2; ++kk) {
        int q = kk * 4 + (lane >> 4);
        bf16x8 a0 = frag_ld(As, ar, q);
        bf16x8 a1 = frag_ld(As, ar + 16, q);
        bf16x8 b0 = frag_ld(Bs, bc, q);
        bf16x8 b1 = frag_ld(Bs, bc + 16, q);
        acc[0][0] = mfma16(a0, b0, acc[0][0]);
        acc[0][1] = mfma16(a0, b1, acc[0][1]);
        acc[1][0] = mfma16(a1, b0, acc[1][0]);
        acc[1][1] = mfma16(a1, b1, acc[1][1]);
      }
      __syncthreads();
    }
#pragma unroll
    for (int m = 0; m < 2; ++m)
#pragma unroll
      for (int n = 0; n < 2; ++n)
#pragma unroll
        for (int r = 0; r < 4; ++r) {
          int row = m0 + wr * 32 + m * 16 + ((lane >> 4) << 2) + r;
          int col = c0 + wc * 32 + n * 16 + (lane & 15);
          float v = tanh_(acc[m][n][r] + bg[col]);
          outp[(size_t)row * 512 + 256 + col] = f2b(v);
        }
  } else {
    // ---- gates: z = [h|x|0] @ rkTa + b ; h_cur,c_cur ----
    int gb = bid - 512;
    int m0 = (gb & 63) * 64, c0 = (gb >> 6) * 64;
    f32x4 acc[4][2][2] = {};
    for (int kt = 0; kt < 320; kt += 64) {
      stage_tile<64, 256>(HX + (size_t)m0 * 320 + kt, 320, As, tid);
#pragma unroll
      for (int i = 0; i < 8; ++i) {  // 4 gate segments x 64 rows of rkTa
        int slot = i * 256 + tid;
        int off = slot << 4;
        int row = off >> 7;
        int k8 = ((off >> 4) & 7) ^ (row & 7);
        int grow = ((row >> 6) << 8) + c0 + (row & 63);
        gload_lds16((const char*)(rkTa + (size_t)grow * 320 + kt) + (k8 << 4),
                    (char*)Bs + off);
      }
      __syncthreads();
#pragma unroll
      for (int kk = 0; kk < 2; ++kk) {
        int q = kk * 4 + (lane >> 4);
        bf16x8 a0 = frag_ld(As, ar, q);
        bf16x8 a1 = frag_ld(As, ar + 16, q);
#pragma unroll
        for (int s = 0; s < 4; ++s) {
          const u16* B = Bs + s * 4096;
          bf16x8 b0 = frag_ld(B, bc, q);
          bf16x8 b1 = frag_ld(B, bc + 16, q);
          acc[s][0][0] = mfma16(a0, b0, acc[s][0][0]);
          acc[s][0][1] = mfma16(a0, b1, acc[s][0][1]);
          acc[s][1][0] = mfma16(a1, b0, acc[s][1][0]);
          acc[s][1][1] = mfma16(a1, b1, acc[s][1][1]);
        }
      }
      __syncthreads();
    }
#pragma unroll
    for (int m = 0; m < 2; ++m)
#pragma unroll
      for (int r = 0; r < 4; ++r) {
        int node = m0 + wr * 32 + m * 16 + ((lane >> 4) << 2) + r;
#pragma unroll
        for (int n = 0; n < 2; ++n) {
          int hcol = c0 + wc * 32 + n * 16 + (lane & 15);
          float z0 = acc[0][m][n][r] + lbias[hcol];
          float z1 = acc[1][m][n][r] + lbias[256 + hcol];
          float z2 = acc[2][m][n][r] + lbias[512 + hcol];
          float z3 = acc[3][m][n][r] + lbias[768 + hcol];
          float i_ = sigmoid_(z0), f_ = sigmoid_(z1);
          float g_ = tanh_(z2), o_ = sigmoid_(z3);
          float cp = cf32[(size_t)node * 256 + hcol];
          float cc = f_ * cp + i_ * g_;
          float hc = o_ * tanh_(cc);
          HG[(size_t)node * 512 + hcol] = f2b(hc);
          CG[(size_t)node * 512 + hcol] = f2b(cc);
        }
      }
  }
}

// L3: h_upd/c_upd = sigmoid([cur|graph] @ [Wcur;Wprev] + b); z=0 emits out_pred
// and writes HX h-cols + x_{t+1}; z=1 writes cf32. grid(128,2) x 256thr.
__global__ __launch_bounds__(256) void k_merge(
    const u16* __restrict__ HG, const u16* __restrict__ CG,
    const u16* __restrict__ WhT, const u16* __restrict__ WcT,
    const float* __restrict__ bh, const float* __restrict__ bcv,
    const float* __restrict__ Wout, const float* __restrict__ bout,
    u16* __restrict__ HX, u16* __restrict__ HCT, float* __restrict__ cf32,
    float* __restrict__ dout, const float* __restrict__ xin, int t) {
  __shared__ __align__(16) u16 As[32 * 64];
  __shared__ __align__(16) u16 Bs[256 * 64];
  __shared__ float outacc[64];
  int z = blockIdx.y;
  const u16* Ain = z ? CG : HG;
  const u16* WT = z ? WcT : WhT;
  const float* bb = z ? bcv : bh;
  int tid = threadIdx.x, lane = tid & 63, w = tid >> 6;
  int m0 = blockIdx.x * 32;
  if (tid < 64) outacc[tid] = 0.f;
  f32x4 acc[2][4] = {};
  int ar = (lane & 15);
  int bcol = w * 64 + (lane & 15);
  for (int kt = 0; kt < 512; kt += 64) {
    stage_tile<32, 256>(Ain + (size_t)m0 * 512 + kt, 512, As, tid);
    stage_tile<256, 256>(WT + kt, 512, Bs, tid);
    __syncthreads();
#pragma unroll
    for (int kk = 0; kk < 2; ++kk) {
      int q = kk * 4 + (lane >> 4);
      bf16x8 a0 = frag_ld(As, ar, q);
      bf16x8 a1 = frag_ld(As, ar + 16, q);
      bf16x8 b0 = frag_ld(Bs, bcol, q);
      bf16x8 b1 = frag_ld(Bs, bcol + 16, q);
      bf16x8 b2 = frag_ld(Bs, bcol + 32, q);
      bf16x8 b3 = frag_ld(Bs, bcol + 48, q);
      acc[0][0] = mfma16(a0, b0, acc[0][0]);
      acc[0][1] = mfma16(a0, b1, acc[0][1]);
      acc[0][2] = mfma16(a0, b2, acc[0][2]);
      acc[0][3] = mfma16(a0, b3, acc[0][3]);
      acc[1][0] = mfma16(a1, b0, acc[1][0]);
      acc[1][1] = mfma16(a1, b1, acc[1][1]);
      acc[1][2] = mfma16(a1, b2, acc[1][2]);
      acc[1][3] = mfma16(a1, b3, acc[1][3]);
    }
    __syncthreads();
  }
#pragma unroll
  for (int m = 0; m < 2; ++m) {
#pragma unroll
    for (int r = 0; r < 4; ++r) {
      int row_local = m * 16 + ((lane >> 4) << 2) + r;
      int node = m0 + row_local;
      float p0 = 0.f, p1 = 0.f;
#pragma unroll
      for (int n = 0; n < 4; ++n) {
        int col = w * 64 + n * 16 + (lane & 15);
        float v = sigmoid_(acc[m][n][r] + bb[col]);
        if (z == 0) {
          HX[(size_t)node * 320 + col] = f2b(v);
          HCT[(size_t)col * 4096 + node] = f2b(v);
          p0 += v * Wout[col * 2];
          p1 += v * Wout[col * 2 + 1];
        } else {
          HCT[(size_t)(256 + col) * 4096 + node] = f2b(v);
          cf32[(size_t)node * 256 + col] = v;
        }
      }
      if (z == 0) {
#pragma unroll
        for (int off = 1; off < 16; off <<= 1) {
          p0 += __shfl_xor(p0, off);
          p1 += __shfl_xor(p1, off);
        }
        if ((lane & 15) == 0) {
          atomicAdd(&outacc[row_local * 2], p0);
          atomicAdd(&outacc[row_local * 2 + 1], p1);
        }
      }
    }
  }
  if (z == 0 && t + 1 < NT) {
    for (int i = tid; i < 512; i += 256) {
      int node = m0 + (i >> 4), d = i & 15;
      HX[(size_t)node * 320 + 256 + d] =
          f2b(xin[(size_t)node * (NT * 16) + (t + 1) * 16 + d]);
    }
  }
  __syncthreads();
  if (z == 0 && tid < 64) {
    int row = tid >> 1, p = tid & 1;
    dout[(size_t)(m0 + row) * (NT * 2) + t * 2 + p] = outacc[tid] + bout[p];
  }
}

extern "C" void kernel_launch(void* const* d_in, const int* in_sizes, int n_in,
                              void* d_out, int out_size, void* d_ws, size_t ws_size,
                              hipStream_t stream) {
  (void)in_sizes; (void)n_in; (void)out_size;
  const float* inputs = (const float*)d_in[0];
  const float* A      = (const float*)d_in[1];
  const float* kern   = (const float*)d_in[2];
  const float* rk     = (const float*)d_in[3];
  const float* lbias  = (const float*)d_in[4];
  const float* wgh    = (const float*)d_in[5];
  const float* bgh    = (const float*)d_in[6];
  const float* wgc    = (const float*)d_in[7];
  const float* bgc    = (const float*)d_in[8];
  const float* whc    = (const float*)d_in[9];
  const float* whp    = (const float*)d_in[10];
  const float* bh     = (const float*)d_in[11];
  const float* wcc    = (const float*)d_in[12];
  const float* wcp    = (const float*)d_in[13];
  const float* bcv    = (const float*)d_in[14];
  const float* wout   = (const float*)d_in[15];
  const float* bout   = (const float*)d_in[16];
  float* dout = (float*)d_out;

  // layout: fixed part = 54.4 MB; Spb = nsplit*4.19 MB (bf16 partials)
  int nsplit = (ws_size >= 71200000) ? 4 : 2;

  char* p = (char*)d_ws;
  u16* Abf  = (u16*)p; p += (size_t)4096 * 4096 * 2;   // 33.55 MB
  u16* HX   = (u16*)p; p += (size_t)4096 * 320 * 2;    // [h(256)|x(16)|0(48)]
  u16* HCT  = (u16*)p; p += (size_t)4096 * 512 * 2;    // [512][4096] transposed
  float* cf32 = (float*)p; p += (size_t)4096 * 256 * 4;
  u16* Spb  = (u16*)p; p += (size_t)nsplit * 4096 * 512 * 2;  // bf16 partials
  u16* HG   = (u16*)p; p += (size_t)4096 * 512 * 2;    // [h_cur|h_graph]
  u16* CG   = (u16*)p; p += (size_t)4096 * 512 * 2;    // [c_cur|c_graph]
  u16* rkTa = (u16*)p; p += (size_t)1024 * 320 * 2;    // augmented [rk;kern;0]
  u16* WgThp = (u16*)p; p += (size_t)65536 * 2;
  u16* WgTcp = (u16*)p; p += (size_t)65536 * 2;
  u16* WhTp  = (u16*)p; p += (size_t)131072 * 2;
  u16* WcTp  = (u16*)p; p += (size_t)131072 * 2;

  k_convA<<<8192, 256, 0, stream>>>(A, Abf);
  // zero HX + HCT + cf32 (contiguous, 11,010,048 B = 688,128 float4)
  k_zero<<<2688, 256, 0, stream>>>((float4*)HX);
  k_x0<<<256, 256, 0, stream>>>(inputs, HX);
  k_prep<<<2816, 256, 0, stream>>>(rk, kern, wgh, wgc, whc, whp, wcc, wcp,
                                   rkTa, WgThp, WgTcp, WhTp, WcTp);

  for (int t = 0; t < NT; ++t) {
    k_big<<<128 * nsplit, 256, 0, stream>>>(Abf, HCT, Spb, nsplit);
    k_phase2<<<768, 256, 0, stream>>>(Spb, nsplit, HX, rkTa, cf32, lbias,
                                      WgThp, WgTcp, bgh, bgc, HG, CG);
    k_merge<<<dim3(128, 2), 256, 0, stream>>>(HG, CG, WhTp, WcTp, bh, bcv, wout,
                                              bout, HX, HCT, cf32, dout, inputs, t);
  }
}